// Round 13
// baseline (284.692 us; speedup 1.0000x reference)
//
#include <hip/hip_runtime.h>
#include <hip/hip_cooperative_groups.h>

namespace cg = cooperative_groups;

// CGCConv: out = (scatter_add(ew*pr[src]*x[src], dst) + x) @ W.T + b
// N=50000, E=800000, D=96, fp32.
//
// Round 13: ONE persistent cooperative kernel (phases = R11's 5 kernels,
// grid.sync() between; bodies verbatim R11):
//   Z: zero cur1                     P: binA bucket-bin + bf16 cvt of x
//   S: per-bucket counting sort      L: pull-aggregate (bf16 gathers)
//   G: MFMA 16x16x32 bf16 GEMM epilogue
// Kills 4 launch gaps + narrow-kernel drain. LDS = 36.3KB union.
// Grid sized by occupancy query so all blocks are co-resident (required
// for this_grid().sync(); also gives cross-XCD visibility between phases).

constexpr int NN = 50000;
constexpr int NE = 800000;
constexpr int DD = 96;
constexpr int NB = 196;                       // buckets: dst>>8 (256 nodes)
constexpr int CAPB = 4608;                    // mu=4082 + 8 sigma
constexpr int EPB = 4096;                     // edges per binA block
constexpr int NBLK = (NE + EPB - 1) / EPB;    // 196
constexpr int NCVT_T = (NN * DD / 4 + 511) / 512;  // 2344 cvt tiles
constexpr int GRID_MAX = 1024;

using s8v = __attribute__((ext_vector_type(8))) short;   // 8 bf16
using f4v = __attribute__((ext_vector_type(4))) float;   // 4 fp32

__device__ inline unsigned short f2bf(float f) {    // RNE fp32->bf16
    unsigned u = __float_as_uint(f);
    return (unsigned short)((u + 0x7FFFu + ((u >> 16) & 1u)) >> 16);
}
__device__ inline float bfh(unsigned short v) {
    return __uint_as_float((unsigned)v << 16);
}
__device__ inline unsigned long long pack_e(int meta, float c) {
    return (unsigned long long)(unsigned)meta |
           ((unsigned long long)(unsigned)__float_as_uint(c) << 32);
}

__global__ __launch_bounds__(512)
void k_mega(const int* __restrict__ src, const int* __restrict__ dst,
            const float* __restrict__ ew, const float* __restrict__ pr,
            const float4* __restrict__ x4, ushort4* __restrict__ y16v,
            unsigned long long* __restrict__ stage, int* __restrict__ cur1,
            int* __restrict__ offs, int* __restrict__ counts,
            unsigned short* __restrict__ io16,
            const float* __restrict__ W, const float* __restrict__ bias,
            float* __restrict__ out) {
    __shared__ __align__(16) char smem[37120];
    cg::grid_group grid = cg::this_grid();
    int tid = threadIdx.x, bid = blockIdx.x, G = gridDim.x;

    // ---- Phase Z: zero cur1 ----
    if (bid == 0 && tid < NB) cur1[tid] = 0;
    grid.sync();

    // ---- Phase P: binA (blocks < NBLK) + cvt (all blocks) ----
    if (bid < NBLK) {
        unsigned long long* psort = (unsigned long long*)smem;      // 4096 u64
        int* h  = (int*)(smem + 32768);
        int* gb = (int*)(smem + 33792);
        int* sc = (int*)(smem + 34816);
        for (int i = tid; i < 256; i += 512) h[i] = 0;
        __syncthreads();
        int base = bid * EPB;
        int n = min(EPB, NE - base);

        unsigned long long ent[8]; int bkt[8]; int lrk[8];
        #pragma unroll
        for (int j = 0; j < 8; j++) {
            int e = base + j * 512 + tid;
            bkt[j] = -1;
            if (e < NE) {
                int d = dst[e];
                int s = src[e];
                float c = ew[e] * pr[s];
                int bk = d >> 8;
                bkt[j] = bk;
                lrk[j] = atomicAdd(&h[bk], 1);
                ent[j] = pack_e(s | ((d & 255) << 16) | (bk << 24), c);
            }
        }
        __syncthreads();
        if (tid < 256) sc[tid] = h[tid];
        __syncthreads();
        #pragma unroll
        for (int o = 1; o < 256; o <<= 1) {
            int t = 0;
            if (tid < 256 && tid >= o) t = sc[tid - o];
            __syncthreads();
            if (tid < 256) sc[tid] += t;             // inclusive scan
            __syncthreads();
        }
        for (int i = tid; i < NB; i += 512)
            gb[i] = h[i] ? atomicAdd(&cur1[i], h[i]) : 0;
        __syncthreads();
        #pragma unroll
        for (int j = 0; j < 8; j++)
            if (bkt[j] >= 0)
                psort[sc[bkt[j]] - h[bkt[j]] + lrk[j]] = ent[j];
        __syncthreads();
        for (int i = tid; i < n; i += 512) {         // coalesced run writes
            unsigned long long e = psort[i];
            int bk = ((int)(e >> 24)) & 0xff;
            stage[(size_t)bk * CAPB + gb[bk] + (i - (sc[bk] - h[bk]))] = e;
        }
    }
    for (int t = bid; t < NCVT_T; t += G) {          // cvt, all blocks
        int i = t * 512 + tid;
        if (i < NN * DD / 4) {
            float4 v = x4[i];
            y16v[i] = make_ushort4(f2bf(v.x), f2bf(v.y), f2bf(v.z), f2bf(v.w));
        }
    }
    grid.sync();

    // ---- Phase S: per-bucket counting sort -> u32 entries ----
    for (int b = bid; b < NB; b += G) {
        unsigned* ssort = (unsigned*)smem;           // CAPB u32 = 18.4KB
        int* h  = (int*)(smem + 18432);
        int* sc = (int*)(smem + 19456);
        size_t base = (size_t)b * CAPB;
        int n = cur1[b];

        for (int i = tid; i < 256; i += 512) h[i] = 0;
        __syncthreads();

        unsigned e32[9]; int dl[9]; int lrk[9];
        int m = 0;
        for (int i = tid; i < n; i += 512) {
            unsigned long long e = stage[base + i];
            int dloc = ((int)(e >> 16)) & 0xff;
            unsigned cb = (unsigned)(e >> 32);       // coef fp32 bits
            unsigned cbf = (cb + 0x7FFFu + ((cb >> 16) & 1u)) >> 16;  // bf16
            e32[m] = ((unsigned)e & 0xffffu) | (cbf << 16);
            dl[m] = dloc;
            lrk[m] = atomicAdd(&h[dloc], 1);
            m++;
        }
        __syncthreads();
        if (tid < 256) sc[tid] = h[tid];
        __syncthreads();
        #pragma unroll
        for (int o = 1; o < 256; o <<= 1) {
            int t = 0;
            if (tid < 256 && tid >= o) t = sc[tid - o];
            __syncthreads();
            if (tid < 256) sc[tid] += t;             // inclusive
            __syncthreads();
        }
        m = 0;
        for (int i = tid; i < n; i += 512) {
            ssort[sc[dl[m]] - h[dl[m]] + lrk[m]] = e32[m];
            m++;
        }
        __syncthreads();
        unsigned* outp = (unsigned*)(stage + base);  // first half of own region
        for (int i = tid; i < n; i += 512) outp[i] = ssort[i];
        if (tid < 256) {
            int d = (b << 8) + tid;
            if (d < NN) {
                offs[d] = (int)(2 * base) + sc[tid] - h[tid];   // u32 index
                counts[d] = h[tid];
            }
        }
        __syncthreads();
    }
    grid.sync();

    // ---- Phase L: pull-aggregate (no LDS) ----
    {
        const ushort4* yv = (const ushort4*)y16v;
        const unsigned* ep = (const unsigned*)stage;
        ushort4* iov = (ushort4*)io16;
        int ngrp = (NN + 15) / 16;                   // 16 nodes / block-iter
        int sub = tid >> 5, lane = tid & 31;
        for (int gi = bid; gi < ngrp; gi += G) {
            int g = gi * 16 + sub;
            if (g >= NN || lane >= 24) continue;
            int beg = offs[g];
            int deg = counts[g];
            float ax = 0.f, ay = 0.f, az = 0.f, aw = 0.f;
            int k = 0;
            for (; k + 8 <= deg; k += 8) {
                unsigned e[8];
                #pragma unroll
                for (int j = 0; j < 8; j++) e[j] = ep[beg + k + j];
                ushort4 u[8];
                #pragma unroll
                for (int j = 0; j < 8; j++)
                    u[j] = yv[(size_t)(e[j] & 0xffff) * 24 + lane];
                #pragma unroll
                for (int j = 0; j < 8; j++) {
                    float c = bfh((unsigned short)(e[j] >> 16));
                    ax += c * bfh(u[j].x);
                    ay += c * bfh(u[j].y);
                    az += c * bfh(u[j].z);
                    aw += c * bfh(u[j].w);
                }
            }
            for (; k + 4 <= deg; k += 4) {
                unsigned e[4];
                #pragma unroll
                for (int j = 0; j < 4; j++) e[j] = ep[beg + k + j];
                ushort4 u[4];
                #pragma unroll
                for (int j = 0; j < 4; j++)
                    u[j] = yv[(size_t)(e[j] & 0xffff) * 24 + lane];
                #pragma unroll
                for (int j = 0; j < 4; j++) {
                    float c = bfh((unsigned short)(e[j] >> 16));
                    ax += c * bfh(u[j].x);
                    ay += c * bfh(u[j].y);
                    az += c * bfh(u[j].z);
                    aw += c * bfh(u[j].w);
                }
            }
            for (; k < deg; k++) {
                unsigned e = ep[beg + k];
                ushort4 u = yv[(size_t)(e & 0xffff) * 24 + lane];
                float c = bfh((unsigned short)(e >> 16));
                ax += c * bfh(u.x);
                ay += c * bfh(u.y);
                az += c * bfh(u.z);
                aw += c * bfh(u.w);
            }
            float4 xn = x4[(size_t)g * 24 + lane];
            iov[(size_t)g * 24 + lane] = make_ushort4(
                f2bf(ax + xn.x), f2bf(ay + xn.y), f2bf(az + xn.z), f2bf(aw + xn.w));
        }
    }
    grid.sync();

    // ---- Phase G: MFMA GEMM epilogue ----
    {
        short* bfr = (short*)smem;                   // 18 frags x 64 x 8 bf16
        for (int i = tid; i < 18 * 512; i += 512) {
            int f = i >> 9, r = i & 511;
            int lane = r >> 3, j = r & 7;
            int ks = f / 6, nt = f - 6 * ks;
            int n = nt * 16 + (lane & 15);
            int k = ks * 32 + (lane >> 4) * 8 + j;
            bfr[i] = (short)f2bf(W[n * DD + k]);
        }
        __syncthreads();

        int wave = tid >> 6, lane = tid & 63;
        int quad = lane >> 4, m16 = lane & 15;
        int niter = (NN + 127) / 128;                // 128 rows / block-iter
        for (int it = bid; it < niter; it += G) {
            int r0 = it * 128 + wave * 16;
            int rowa = r0 + m16;
            if (rowa >= NN) rowa = NN - 1;           // clamped read, masked store

            f4v acc[6];
            #pragma unroll
            for (int nt = 0; nt < 6; nt++) acc[nt] = (f4v){0.f, 0.f, 0.f, 0.f};

            #pragma unroll
            for (int ks = 0; ks < 3; ks++) {
                s8v a = *(const s8v*)(io16 + (size_t)rowa * DD + ks * 32 + quad * 8);
                #pragma unroll
                for (int nt = 0; nt < 6; nt++) {
                    s8v bb = *(const s8v*)&bfr[((ks * 6 + nt) * 64 + lane) * 8];
                    acc[nt] = __builtin_amdgcn_mfma_f32_16x16x32_bf16(a, bb, acc[nt],
                                                                      0, 0, 0);
                }
            }

            #pragma unroll
            for (int nt = 0; nt < 6; nt++) {
                float bv = bias[nt * 16 + m16];
                #pragma unroll
                for (int reg = 0; reg < 4; reg++) {
                    int rr = r0 + quad * 4 + reg;
                    if (rr < NN)
                        out[(size_t)rr * DD + nt * 16 + m16] = acc[nt][reg] + bv;
                }
            }
        }
    }
}

extern "C" void kernel_launch(void* const* d_in, const int* in_sizes, int n_in,
                              void* d_out, int out_size, void* d_ws, size_t ws_size,
                              hipStream_t stream) {
    const float* x  = (const float*)d_in[0];
    const int*   ei = (const int*)d_in[1];   // [2,E]: [0..E)=src, [E..2E)=dst
    const float* ew = (const float*)d_in[2];
    const float* pr = (const float*)d_in[3];
    const float* W  = (const float*)d_in[4];
    const float* b  = (const float*)d_in[5];
    float* out = (float*)d_out;

    // ws layout (~26.8 MB)
    unsigned long long* stage = (unsigned long long*)d_ws;       // NB*CAPB u64
    unsigned short* y16 = (unsigned short*)(stage + (size_t)NB * CAPB);  // 9.6MB
    int* cur1   = (int*)(y16 + (size_t)NN * DD);      // 196
    int* offs   = cur1 + NB;                          // 50000
    int* counts = offs + NN;                          // 50000
    unsigned short* io16 = (unsigned short*)(counts + NN);       // 9.6MB

    const int* src = ei;
    const int* dst = ei + NE;
    const float4* x4 = (const float4*)x;
    ushort4* y16v = (ushort4*)y16;

    int nb = 0;
    hipOccupancyMaxActiveBlocksPerMultiprocessor(&nb, (const void*)k_mega, 512, 0);
    if (nb < 1) nb = 1;
    long grid = (long)nb * 256;
    if (grid > GRID_MAX) grid = GRID_MAX;

    void* args[] = {(void*)&src, (void*)&dst, (void*)&ew, (void*)&pr,
                    (void*)&x4, (void*)&y16v, (void*)&stage, (void*)&cur1,
                    (void*)&offs, (void*)&counts, (void*)&io16,
                    (void*)&W, (void*)&b, (void*)&out};
    hipLaunchCooperativeKernel((const void*)k_mega, dim3((unsigned)grid), dim3(512),
                               args, 0, stream);
}

// Round 14
// 148.935 us; speedup vs baseline: 1.9115x; 1.9115x over previous
//
#include <hip/hip_runtime.h>

// CGCConv: out = (scatter_add(ew*pr[src]*x[src], dst) + x) @ W.T + b
// N=50000, E=800000, D=96, fp32.
//
// Round 14 = R11 structure (141.5us best) + occupancy-free pull+gemm fusion.
// R13 mega-kernel regressed (284us): coupling the latency-bound pull to the
// sort/gemm resource footprint halved resident waves. Here the fusion is
// per-row (out[r] needs only row r of aggr+x) => no grid barrier, and the
// only LDS is a 64x104 bf16 X-tile (13.3KB, 8 blocks/CU wave-capped — same
// pull occupancy as R11). W is pre-converted to MFMA-ready bf16 frags by
// k_prep into ws (18.4KB, L1-resident in pullgemm). Kills io16 19.2MB
// write+read + one launch gap. k_zero replaced by hipMemsetAsync.
// Pipeline (4 dispatches): memset(cur1) -> prep -> sortB -> pullgemm.

constexpr int NN = 50000;
constexpr int NE = 800000;
constexpr int DD = 96;
constexpr int NB = 196;                       // buckets: dst>>8 (256 nodes)
constexpr int CAPB = 4608;                    // mu=4082 + 8 sigma
constexpr int EPB = 4096;                     // edges per binA block
constexpr int NBLK = (NE + EPB - 1) / EPB;    // 196
constexpr int NCVT_T = (NN * DD / 4 + 511) / 512;  // 2344 cvt tiles
constexpr int XS = 104;                       // X-tile stride (16B-mult, <=2-way)

using s8v = __attribute__((ext_vector_type(8))) short;   // 8 bf16
using f4v = __attribute__((ext_vector_type(4))) float;   // 4 fp32

__device__ inline unsigned short f2bf(float f) {    // RNE fp32->bf16
    unsigned u = __float_as_uint(f);
    return (unsigned short)((u + 0x7FFFu + ((u >> 16) & 1u)) >> 16);
}
__device__ inline float bfh(unsigned short v) {
    return __uint_as_float((unsigned)v << 16);
}
__device__ inline unsigned long long pack_e(int meta, float c) {
    return (unsigned long long)(unsigned)meta |
           ((unsigned long long)(unsigned)__float_as_uint(c) << 32);
}

// Blocks [0,NBLK): bucket-bin. Blocks [NBLK,NBLK+NCVT_T): y16=bf16(x).
// Block NBLK+NCVT_T: W -> MFMA-ready bf16 B-frags (frag f=ks*6+nt; lane
// holds B[k][n], n=nt*16+(lane&15), k=ks*32+(lane>>4)*8+j).
__global__ __launch_bounds__(512) void k_prep(const int* __restrict__ src,
                                              const int* __restrict__ dst,
                                              const float* __restrict__ ew,
                                              const float* __restrict__ pr,
                                              int* __restrict__ cur1,
                                              unsigned long long* __restrict__ stage,
                                              const float4* __restrict__ x4,
                                              ushort4* __restrict__ y16v,
                                              const float* __restrict__ W,
                                              unsigned short* __restrict__ wfrag) {
    int tid = threadIdx.x;
    if (blockIdx.x >= NBLK) {
        int t = blockIdx.x - NBLK;
        if (t < NCVT_T) {                     // cvt phase
            int i = t * 512 + tid;
            if (i < NN * DD / 4) {
                float4 v = x4[i];
                y16v[i] = make_ushort4(f2bf(v.x), f2bf(v.y), f2bf(v.z), f2bf(v.w));
            }
        } else {                              // wfrag phase (18*64*8 = 9216)
            for (int i = tid; i < 18 * 512; i += 512) {
                int f = i >> 9, r = i & 511;
                int lane = r >> 3, j = r & 7;
                int ks = f / 6, nt = f - 6 * ks;
                int n = nt * 16 + (lane & 15);
                int k = ks * 32 + (lane >> 4) * 8 + j;
                wfrag[i] = f2bf(W[n * DD + k]);
            }
        }
        return;
    }
    __shared__ int h[256];
    __shared__ int gb[256];
    __shared__ int sc[256];
    __shared__ unsigned long long sorted[EPB];   // 32 KB
    for (int i = tid; i < 256; i += 512) h[i] = 0;
    __syncthreads();
    int base = blockIdx.x * EPB;
    int n = min(EPB, NE - base);

    unsigned long long ent[8]; int bkt[8]; int lrk[8];
    #pragma unroll
    for (int j = 0; j < 8; j++) {
        int e = base + j * 512 + tid;
        bkt[j] = -1;
        if (e < NE) {
            int d = dst[e];
            int s = src[e];
            float c = ew[e] * pr[s];
            int bk = d >> 8;
            bkt[j] = bk;
            lrk[j] = atomicAdd(&h[bk], 1);
            ent[j] = pack_e(s | ((d & 255) << 16) | (bk << 24), c);
        }
    }
    __syncthreads();
    if (tid < 256) sc[tid] = h[tid];
    __syncthreads();
    #pragma unroll
    for (int o = 1; o < 256; o <<= 1) {
        int t = 0;
        if (tid < 256 && tid >= o) t = sc[tid - o];
        __syncthreads();
        if (tid < 256) sc[tid] += t;             // inclusive scan
        __syncthreads();
    }
    for (int i = tid; i < NB; i += 512)
        gb[i] = h[i] ? atomicAdd(&cur1[i], h[i]) : 0;
    __syncthreads();
    #pragma unroll
    for (int j = 0; j < 8; j++)
        if (bkt[j] >= 0)
            sorted[sc[bkt[j]] - h[bkt[j]] + lrk[j]] = ent[j];
    __syncthreads();
    for (int i = tid; i < n; i += 512) {         // coalesced run writes
        unsigned long long e = sorted[i];
        int bk = ((int)(e >> 24)) & 0xff;
        stage[(size_t)bk * CAPB + gb[bk] + (i - (sc[bk] - h[bk]))] = e;
    }
}

// Per-bucket counting sort by dloc -> u32 {src | coef_bf16<<16} entries
// (first half of own region; block-private => safe).
__global__ __launch_bounds__(512) void k_sortB(unsigned long long* __restrict__ stage,
                                               const int* __restrict__ cur1,
                                               int* __restrict__ offs,
                                               int* __restrict__ counts) {
    __shared__ int h[256];
    __shared__ int sc[256];
    __shared__ unsigned sorted[CAPB];            // u32, 18.4 KB
    int b = blockIdx.x;
    int tid = threadIdx.x;
    size_t base = (size_t)b * CAPB;
    int n = cur1[b];

    for (int i = tid; i < 256; i += 512) h[i] = 0;
    __syncthreads();

    unsigned e32[9]; int dl[9]; int lrk[9];
    int m = 0;
    for (int i = tid; i < n; i += 512) {
        unsigned long long e = stage[base + i];
        int dloc = ((int)(e >> 16)) & 0xff;
        unsigned cb = (unsigned)(e >> 32);       // coef fp32 bits
        unsigned cbf = (cb + 0x7FFFu + ((cb >> 16) & 1u)) >> 16;  // bf16
        e32[m] = ((unsigned)e & 0xffffu) | (cbf << 16);
        dl[m] = dloc;
        lrk[m] = atomicAdd(&h[dloc], 1);
        m++;
    }
    __syncthreads();
    if (tid < 256) sc[tid] = h[tid];
    __syncthreads();
    #pragma unroll
    for (int o = 1; o < 256; o <<= 1) {
        int t = 0;
        if (tid < 256 && tid >= o) t = sc[tid - o];
        __syncthreads();
        if (tid < 256) sc[tid] += t;             // inclusive
        __syncthreads();
    }
    m = 0;
    for (int i = tid; i < n; i += 512) {
        sorted[sc[dl[m]] - h[dl[m]] + lrk[m]] = e32[m];
        m++;
    }
    __syncthreads();
    unsigned* outp = (unsigned*)(stage + base);  // first half of own region
    for (int i = tid; i < n; i += 512) outp[i] = sorted[i];
    if (tid < 256) {
        int d = (b << 8) + tid;
        if (d < NN) {
            offs[d] = (int)(2 * base) + sc[tid] - h[tid];   // u32 index
            counts[d] = h[tid];
        }
    }
}

// Fused pull + MFMA GEMM. Block = 256 threads, 64 rows.
// Pull: 8 groups x 32 lanes; each group aggregates 8 nodes (R11 body),
// writing bf16(aggr+x) into the LDS X-tile (stride 104: 16B-aligned b128,
// <=2-way banks). Then __syncthreads (block-local!) and each of 4 waves
// MFMAs a 16-row strip: A from X-tile, B-frags from global wfrag
// (L1-resident 18.4KB), C/D verified layout. Only 13.3KB LDS => pull phase
// keeps R11's wave-capped occupancy.
__global__ __launch_bounds__(256) void k_pullgemm(const ushort4* __restrict__ y16v,
                                                  const float4* __restrict__ x4,
                                                  const int* __restrict__ offs,
                                                  const int* __restrict__ counts,
                                                  const unsigned* __restrict__ ep,
                                                  const unsigned short* __restrict__ wfrag,
                                                  const float* __restrict__ bias,
                                                  float* __restrict__ out) {
    __shared__ unsigned short xt[64 * XS];       // 13.3 KB
    int tid = threadIdx.x;
    int sub = tid >> 5, lane = tid & 31;
    int gbase = blockIdx.x * 64;

    #pragma unroll
    for (int i = 0; i < 8; i++) {
        int lr = sub * 8 + i;
        int g = gbase + lr;
        if (g < NN && lane < 24) {
            int beg = offs[g];
            int deg = counts[g];
            float ax = 0.f, ay = 0.f, az = 0.f, aw = 0.f;
            int k = 0;
            for (; k + 8 <= deg; k += 8) {
                unsigned e[8];
                #pragma unroll
                for (int j = 0; j < 8; j++) e[j] = ep[beg + k + j];
                ushort4 u[8];
                #pragma unroll
                for (int j = 0; j < 8; j++)
                    u[j] = y16v[(size_t)(e[j] & 0xffff) * 24 + lane];
                #pragma unroll
                for (int j = 0; j < 8; j++) {
                    float c = bfh((unsigned short)(e[j] >> 16));
                    ax += c * bfh(u[j].x);
                    ay += c * bfh(u[j].y);
                    az += c * bfh(u[j].z);
                    aw += c * bfh(u[j].w);
                }
            }
            for (; k + 4 <= deg; k += 4) {
                unsigned e[4];
                #pragma unroll
                for (int j = 0; j < 4; j++) e[j] = ep[beg + k + j];
                ushort4 u[4];
                #pragma unroll
                for (int j = 0; j < 4; j++)
                    u[j] = y16v[(size_t)(e[j] & 0xffff) * 24 + lane];
                #pragma unroll
                for (int j = 0; j < 4; j++) {
                    float c = bfh((unsigned short)(e[j] >> 16));
                    ax += c * bfh(u[j].x);
                    ay += c * bfh(u[j].y);
                    az += c * bfh(u[j].z);
                    aw += c * bfh(u[j].w);
                }
            }
            for (; k < deg; k++) {
                unsigned e = ep[beg + k];
                ushort4 u = y16v[(size_t)(e & 0xffff) * 24 + lane];
                float c = bfh((unsigned short)(e >> 16));
                ax += c * bfh(u.x);
                ay += c * bfh(u.y);
                az += c * bfh(u.z);
                aw += c * bfh(u.w);
            }
            float4 xn = x4[(size_t)g * 24 + lane];
            *(ushort4*)&xt[lr * XS + lane * 4] = make_ushort4(
                f2bf(ax + xn.x), f2bf(ay + xn.y), f2bf(az + xn.z), f2bf(aw + xn.w));
        }
    }
    __syncthreads();

    int wave = tid >> 6, l64 = tid & 63;
    int quad = l64 >> 4, m16 = l64 & 15;
    int r0 = wave * 16;

    f4v acc[6];
    #pragma unroll
    for (int nt = 0; nt < 6; nt++) acc[nt] = (f4v){0.f, 0.f, 0.f, 0.f};

    #pragma unroll
    for (int ks = 0; ks < 3; ks++) {
        s8v a = *(const s8v*)&xt[(r0 + m16) * XS + ks * 32 + quad * 8];
        #pragma unroll
        for (int nt = 0; nt < 6; nt++) {
            s8v bb = *(const s8v*)&wfrag[((ks * 6 + nt) * 64 + l64) * 8];
            acc[nt] = __builtin_amdgcn_mfma_f32_16x16x32_bf16(a, bb, acc[nt], 0, 0, 0);
        }
    }

    #pragma unroll
    for (int nt = 0; nt < 6; nt++) {
        float bv = bias[nt * 16 + m16];
        #pragma unroll
        for (int reg = 0; reg < 4; reg++) {
            int rr = gbase + r0 + quad * 4 + reg;
            if (rr < NN)
                out[(size_t)rr * DD + nt * 16 + m16] = acc[nt][reg] + bv;
        }
    }
}

extern "C" void kernel_launch(void* const* d_in, const int* in_sizes, int n_in,
                              void* d_out, int out_size, void* d_ws, size_t ws_size,
                              hipStream_t stream) {
    const float* x  = (const float*)d_in[0];
    const int*   ei = (const int*)d_in[1];   // [2,E]: [0..E)=src, [E..2E)=dst
    const float* ew = (const float*)d_in[2];
    const float* pr = (const float*)d_in[3];
    const float* W  = (const float*)d_in[4];
    const float* b  = (const float*)d_in[5];
    float* out = (float*)d_out;

    // ws layout (~17.2 MB)
    unsigned long long* stage = (unsigned long long*)d_ws;       // NB*CAPB u64
    unsigned short* y16 = (unsigned short*)(stage + (size_t)NB * CAPB);  // 9.6MB
    int* cur1   = (int*)(y16 + (size_t)NN * DD);      // 196
    int* offs   = cur1 + NB;                          // 50000
    int* counts = offs + NN;                          // 50000
    unsigned short* wfrag = (unsigned short*)(counts + NN);      // 9216 u16

    const int* src = ei;
    const int* dst = ei + NE;

    hipMemsetAsync(cur1, 0, NB * sizeof(int), stream);
    k_prep<<<NBLK + NCVT_T + 1, 512, 0, stream>>>(src, dst, ew, pr, cur1, stage,
                                                  (const float4*)x, (ushort4*)y16,
                                                  W, wfrag);
    k_sortB<<<NB, 512, 0, stream>>>(stage, cur1, offs, counts);
    k_pullgemm<<<(NN + 63) / 64, 256, 0, stream>>>((const ushort4*)y16,
                                                   (const float4*)x, offs, counts,
                                                   (const unsigned*)stage, wfrag,
                                                   b, out);
}

// Round 16
// 140.980 us; speedup vs baseline: 2.0194x; 1.0564x over previous
//
#include <hip/hip_runtime.h>

// CGCConv: out = (scatter_add(ew*pr[src]*x[src], dst) + x) @ W.T + b
// N=50000, E=800000, D=96, fp32.
//
// Round 16 = Round 15 resubmitted (GPU broker timeout — never ran).
// = Round 11 verbatim (141.5us, best) + hipMemsetAsync for cur1
// (one fewer dispatch). R12 (padded vec entries) neutral; R13 (coop mega)
// and R14 (pull+gemm fusion) regressed — the latency-bound pull needs max
// resident waves (6250 blocks, 20-52 VGPR, 0 LDS); any structure that
// shrinks its thread pool (R7 LDS, R13 VGPR/LDS, R14 grid) loses more than
// saved traffic/launches gain.
// Pipeline (4 dispatches): memset(cur1) -> prep -> sortB -> pull -> gemm.

constexpr int NN = 50000;
constexpr int NE = 800000;
constexpr int DD = 96;
constexpr int NB = 196;                       // buckets: dst>>8 (256 nodes)
constexpr int CAPB = 4608;                    // mu=4082 + 8 sigma
constexpr int EPB = 4096;                     // edges per binA block
constexpr int NBLK = (NE + EPB - 1) / EPB;    // 196
constexpr int NCVT = (NN * DD / 4 + 511) / 512;  // 2344 cvt blocks

using s8v = __attribute__((ext_vector_type(8))) short;   // 8 bf16
using f4v = __attribute__((ext_vector_type(4))) float;   // 4 fp32

__device__ inline unsigned short f2bf(float f) {    // RNE fp32->bf16
    unsigned u = __float_as_uint(f);
    return (unsigned short)((u + 0x7FFFu + ((u >> 16) & 1u)) >> 16);
}
__device__ inline float bfh(unsigned short v) {
    return __uint_as_float((unsigned)v << 16);
}
__device__ inline unsigned long long pack_e(int meta, float c) {
    return (unsigned long long)(unsigned)meta |
           ((unsigned long long)(unsigned)__float_as_uint(c) << 32);
}

// Blocks [0,NBLK): bin 4096 edges -> LDS counting-sort by bucket -> coalesced
// run writes. Entry u64 = {src:16 | dloc:8 | bucket:8 | coef_f32:32}.
// Blocks [NBLK,..): y16 = bf16(x).
__global__ __launch_bounds__(512) void k_prep(const int* __restrict__ src,
                                              const int* __restrict__ dst,
                                              const float* __restrict__ ew,
                                              const float* __restrict__ pr,
                                              int* __restrict__ cur1,
                                              unsigned long long* __restrict__ stage,
                                              const float4* __restrict__ x4,
                                              ushort4* __restrict__ y16v) {
    int tid = threadIdx.x;
    if (blockIdx.x >= NBLK) {                 // cvt phase
        int i = (blockIdx.x - NBLK) * 512 + tid;
        if (i < NN * DD / 4) {
            float4 v = x4[i];
            y16v[i] = make_ushort4(f2bf(v.x), f2bf(v.y), f2bf(v.z), f2bf(v.w));
        }
        return;
    }
    __shared__ int h[256];
    __shared__ int gb[256];
    __shared__ int sc[256];
    __shared__ unsigned long long sorted[EPB];   // 32 KB
    for (int i = tid; i < 256; i += 512) h[i] = 0;
    __syncthreads();
    int base = blockIdx.x * EPB;
    int n = min(EPB, NE - base);

    unsigned long long ent[8]; int bkt[8]; int lrk[8];
    #pragma unroll
    for (int j = 0; j < 8; j++) {
        int e = base + j * 512 + tid;
        bkt[j] = -1;
        if (e < NE) {
            int d = dst[e];
            int s = src[e];
            float c = ew[e] * pr[s];
            int bk = d >> 8;
            bkt[j] = bk;
            lrk[j] = atomicAdd(&h[bk], 1);
            ent[j] = pack_e(s | ((d & 255) << 16) | (bk << 24), c);
        }
    }
    __syncthreads();
    if (tid < 256) sc[tid] = h[tid];
    __syncthreads();
    #pragma unroll
    for (int o = 1; o < 256; o <<= 1) {
        int t = 0;
        if (tid < 256 && tid >= o) t = sc[tid - o];
        __syncthreads();
        if (tid < 256) sc[tid] += t;             // inclusive scan
        __syncthreads();
    }
    for (int i = tid; i < NB; i += 512)
        gb[i] = h[i] ? atomicAdd(&cur1[i], h[i]) : 0;
    __syncthreads();
    #pragma unroll
    for (int j = 0; j < 8; j++)
        if (bkt[j] >= 0)
            sorted[sc[bkt[j]] - h[bkt[j]] + lrk[j]] = ent[j];
    __syncthreads();
    for (int i = tid; i < n; i += 512) {         // coalesced run writes
        unsigned long long e = sorted[i];
        int bk = ((int)(e >> 24)) & 0xff;
        stage[(size_t)bk * CAPB + gb[bk] + (i - (sc[bk] - h[bk]))] = e;
    }
}

// Per-bucket counting sort by dloc; emits u32 {src | coef_bf16<<16} into the
// first half of the block's own region (all reads precede writes => safe).
__global__ __launch_bounds__(512) void k_sortB(unsigned long long* __restrict__ stage,
                                               const int* __restrict__ cur1,
                                               int* __restrict__ offs,
                                               int* __restrict__ counts) {
    __shared__ int h[256];
    __shared__ int sc[256];
    __shared__ unsigned sorted[CAPB];            // u32, 18.4 KB
    int b = blockIdx.x;
    int tid = threadIdx.x;
    size_t base = (size_t)b * CAPB;
    int n = cur1[b];

    for (int i = tid; i < 256; i += 512) h[i] = 0;
    __syncthreads();

    unsigned e32[9]; int dl[9]; int lrk[9];
    int m = 0;
    for (int i = tid; i < n; i += 512) {
        unsigned long long e = stage[base + i];
        int dloc = ((int)(e >> 16)) & 0xff;
        unsigned cb = (unsigned)(e >> 32);       // coef fp32 bits
        unsigned cbf = (cb + 0x7FFFu + ((cb >> 16) & 1u)) >> 16;  // bf16
        e32[m] = ((unsigned)e & 0xffffu) | (cbf << 16);
        dl[m] = dloc;
        lrk[m] = atomicAdd(&h[dloc], 1);
        m++;
    }
    __syncthreads();
    if (tid < 256) sc[tid] = h[tid];
    __syncthreads();
    #pragma unroll
    for (int o = 1; o < 256; o <<= 1) {
        int t = 0;
        if (tid < 256 && tid >= o) t = sc[tid - o];
        __syncthreads();
        if (tid < 256) sc[tid] += t;             // inclusive
        __syncthreads();
    }
    m = 0;
    for (int i = tid; i < n; i += 512) {
        sorted[sc[dl[m]] - h[dl[m]] + lrk[m]] = e32[m];
        m++;
    }
    __syncthreads();
    unsigned* outp = (unsigned*)(stage + base);  // first half of own region
    for (int i = tid; i < n; i += 512) outp[i] = sorted[i];
    if (tid < 256) {
        int d = (b << 8) + tid;
        if (d < NN) {
            offs[d] = (int)(2 * base) + sc[tid] - h[tid];   // u32 index
            counts[d] = h[tid];
        }
    }
}

// Pull-aggregate: 8 nodes/block, 32 lanes/node, lanes 0..23 own one ushort4
// (4 bf16 channels, 8B gather). Writes io16 = bf16(aggr + x).
__global__ __launch_bounds__(256) void k_pull(const ushort4* __restrict__ y16v,
                                              const float4* __restrict__ x4,
                                              const int* __restrict__ offs,
                                              const int* __restrict__ counts,
                                              const unsigned* __restrict__ ep,
                                              ushort4* __restrict__ io16v) {
    int g = blockIdx.x * 8 + (threadIdx.x >> 5);
    int lane = threadIdx.x & 31;
    if (g >= NN || lane >= 24) return;
    int beg = offs[g];
    int deg = counts[g];
    float ax = 0.f, ay = 0.f, az = 0.f, aw = 0.f;
    int k = 0;
    for (; k + 8 <= deg; k += 8) {
        unsigned e[8];
        #pragma unroll
        for (int j = 0; j < 8; j++) e[j] = ep[beg + k + j];
        ushort4 u[8];
        #pragma unroll
        for (int j = 0; j < 8; j++)
            u[j] = y16v[(size_t)(e[j] & 0xffff) * 24 + lane];
        #pragma unroll
        for (int j = 0; j < 8; j++) {
            float c = bfh((unsigned short)(e[j] >> 16));
            ax += c * bfh(u[j].x);
            ay += c * bfh(u[j].y);
            az += c * bfh(u[j].z);
            aw += c * bfh(u[j].w);
        }
    }
    for (; k + 4 <= deg; k += 4) {
        unsigned e[4];
        #pragma unroll
        for (int j = 0; j < 4; j++) e[j] = ep[beg + k + j];
        ushort4 u[4];
        #pragma unroll
        for (int j = 0; j < 4; j++)
            u[j] = y16v[(size_t)(e[j] & 0xffff) * 24 + lane];
        #pragma unroll
        for (int j = 0; j < 4; j++) {
            float c = bfh((unsigned short)(e[j] >> 16));
            ax += c * bfh(u[j].x);
            ay += c * bfh(u[j].y);
            az += c * bfh(u[j].z);
            aw += c * bfh(u[j].w);
        }
    }
    for (; k < deg; k++) {
        unsigned e = ep[beg + k];
        ushort4 u = y16v[(size_t)(e & 0xffff) * 24 + lane];
        float c = bfh((unsigned short)(e >> 16));
        ax += c * bfh(u.x);
        ay += c * bfh(u.y);
        az += c * bfh(u.z);
        aw += c * bfh(u.w);
    }
    float4 xn = x4[(size_t)g * 24 + lane];
    io16v[(size_t)g * 24 + lane] = make_ushort4(f2bf(ax + xn.x), f2bf(ay + xn.y),
                                                f2bf(az + xn.z), f2bf(aw + xn.w));
}

// MFMA GEMM: out[r,o] = sum_d io16[r,d]*W[o,d] + b[o], fp32 out.
// Wave = 16-row x 96-col strip. A from global (m=lane&15, k=quad*8+j).
// B-frags pre-swizzled in LDS (B[k][n], n=nt*16+(lane&15), k=ks*32+quad*8+j).
// C/D: col=lane&15, row=quad*4+reg (HW-verified; absmax-confirmed R11).
__global__ __launch_bounds__(256) void k_gemm(const unsigned short* __restrict__ io16,
                                              const float* __restrict__ W,
                                              const float* __restrict__ b,
                                              float* __restrict__ out) {
    __shared__ short bfr[18 * 64 * 8];     // 18 frags x 64 lanes x 8 bf16 = 18.4KB
    int tid = threadIdx.x;
    for (int i = tid; i < 18 * 512; i += 256) {
        int f = i >> 9, r = i & 511;
        int lane = r >> 3, j = r & 7;
        int ks = f / 6, nt = f - 6 * ks;
        int n = nt * 16 + (lane & 15);
        int k = ks * 32 + (lane >> 4) * 8 + j;
        bfr[i] = (short)f2bf(W[n * DD + k]);
    }
    __syncthreads();

    int wave = tid >> 6, lane = tid & 63;
    int quad = lane >> 4, m16 = lane & 15;
    int r0 = blockIdx.x * 64 + wave * 16;
    int rowa = r0 + m16;
    if (rowa >= NN) rowa = NN - 1;           // clamped A read, store masked

    f4v acc[6];
    #pragma unroll
    for (int nt = 0; nt < 6; nt++) acc[nt] = (f4v){0.f, 0.f, 0.f, 0.f};

    #pragma unroll
    for (int ks = 0; ks < 3; ks++) {
        s8v a = *(const s8v*)(io16 + (size_t)rowa * DD + ks * 32 + quad * 8);
        #pragma unroll
        for (int nt = 0; nt < 6; nt++) {
            s8v bb = *(const s8v*)&bfr[((ks * 6 + nt) * 64 + lane) * 8];
            acc[nt] = __builtin_amdgcn_mfma_f32_16x16x32_bf16(a, bb, acc[nt], 0, 0, 0);
        }
    }

    #pragma unroll
    for (int nt = 0; nt < 6; nt++) {
        float bias = b[nt * 16 + m16];
        #pragma unroll
        for (int reg = 0; reg < 4; reg++) {
            int rr = r0 + quad * 4 + reg;
            if (rr < NN)
                out[(size_t)rr * DD + nt * 16 + m16] = acc[nt][reg] + bias;
        }
    }
}

extern "C" void kernel_launch(void* const* d_in, const int* in_sizes, int n_in,
                              void* d_out, int out_size, void* d_ws, size_t ws_size,
                              hipStream_t stream) {
    const float* x  = (const float*)d_in[0];
    const int*   ei = (const int*)d_in[1];   // [2,E]: [0..E)=src, [E..2E)=dst
    const float* ew = (const float*)d_in[2];
    const float* pr = (const float*)d_in[3];
    const float* W  = (const float*)d_in[4];
    const float* b  = (const float*)d_in[5];
    float* out = (float*)d_out;

    // ws layout (~26.8 MB)
    unsigned long long* stage = (unsigned long long*)d_ws;       // NB*CAPB u64
    unsigned short* y16 = (unsigned short*)(stage + (size_t)NB * CAPB);  // 9.6MB
    int* cur1   = (int*)(y16 + (size_t)NN * DD);      // 196
    int* offs   = cur1 + NB;                          // 50000
    int* counts = offs + NN;                          // 50000
    unsigned short* io16 = (unsigned short*)(counts + NN);       // 9.6MB

    const int* src = ei;
    const int* dst = ei + NE;

    hipMemsetAsync(cur1, 0, NB * sizeof(int), stream);
    k_prep<<<NBLK + NCVT, 512, 0, stream>>>(src, dst, ew, pr, cur1, stage,
                                            (const float4*)x, (ushort4*)y16);
    k_sortB<<<NB, 512, 0, stream>>>(stage, cur1, offs, counts);
    k_pull<<<(NN + 7) / 8, 256, 0, stream>>>((const ushort4*)y16, (const float4*)x,
                                             offs, counts, (const unsigned*)stage,
                                             (ushort4*)io16);
    k_gemm<<<(NN + 63) / 64, 256, 0, stream>>>(io16, W, b, out);
}